// Round 2
// baseline (1203.477 us; speedup 1.0000x reference)
//
#include <hip/hip_runtime.h>
#include <hip/hip_bf16.h>
#include <math.h>

#define FIN 32
#define EFD 16
#define GDIM 8
// D = 64, DL = 128 hard-coded throughout

typedef __attribute__((ext_vector_type(8))) short short8;   // 8 bf16 = 4 VGPRs (MFMA A/B frag)
typedef __attribute__((ext_vector_type(4))) float f32x4;    // MFMA C/D frag

static __device__ __forceinline__ float bf2f(unsigned short u) {
  return __uint_as_float(((unsigned)u) << 16);
}
static __device__ __forceinline__ unsigned short f2bf(float f) {
  unsigned u = __float_as_uint(f);
  unsigned r = (u + 0x7FFFu + ((u >> 16) & 1u)) >> 16;  // RNE
  return (unsigned short)r;
}

__global__ void zero_f32(float* __restrict__ p, int n) {
  int i = blockIdx.x * blockDim.x + threadIdx.x;
  if (i < n) p[i] = 0.0f;
}

__global__ void deg_kernel(const int* __restrict__ dst, float* __restrict__ deg, int E) {
  int e = blockIdx.x * blockDim.x + threadIdx.x;
  if (e < E) atomicAdd(&deg[dst[e]], 1.0f);
}

// state = relu(x @ W0^T + b0)   [N,64]; lane = output feature
__global__ void lin0_kernel(const float* __restrict__ x, const float* __restrict__ W0,
                            const float* __restrict__ b0, float* __restrict__ state, int N) {
  int idx = blockIdx.x * blockDim.x + threadIdx.x;
  int n = idx >> 6, d = idx & 63;
  if (n >= N) return;
  float acc = b0[d];
  const float* xr = x + (size_t)n * FIN;
  const float* wr = W0 + (size_t)d * FIN;
  #pragma unroll
  for (int f = 0; f < FIN; ++f) acc += xr[f] * wr[f];
  state[idx] = fmaxf(acc, 0.0f);
}

// hidden(bf16) = relu(edge_attr @ We1^T + be1)   [E,128]
__global__ void edge_mlp1(const float* __restrict__ ea, const float* __restrict__ We1,
                          const float* __restrict__ be1, unsigned short* __restrict__ hidden, int E) {
  int idx = blockIdx.x * blockDim.x + threadIdx.x;
  int e = idx >> 7, l = idx & 127;
  if (e >= E) return;
  float acc = be1[l];
  const float* er = ea + (size_t)e * EFD;
  const float* wr = We1 + (size_t)l * EFD;
  #pragma unroll
  for (int j = 0; j < EFD; ++j) acc += er[j] * wr[j];
  hidden[idx] = f2bf(fmaxf(acc, 0.0f));
}

// We2 fp32 [4096,128] -> bf16 copy
__global__ void conv_we2(const float* __restrict__ We2, unsigned short* __restrict__ We2bf, int n) {
  int i = blockIdx.x * blockDim.x + threadIdx.x;
  if (i < n) We2bf[i] = f2bf(We2[i]);
}

// u[n,o] = sum_i state[n,i] * be2[i*64+o]   (bias term of the per-edge matrix)
__global__ __launch_bounds__(256) void u_kernel(const float* __restrict__ state,
    const float* __restrict__ be2, float* __restrict__ u, int N) {
  int lane = threadIdx.x & 63;
  int n = blockIdx.x * 4 + (threadIdx.x >> 6);
  if (n >= N) return;
  float s = state[(size_t)n * 64 + lane];
  float acc = 0.0f;
  for (int i = 0; i < 64; ++i) acc += __shfl(s, i) * be2[i * 64 + lane];
  u[(size_t)n * 64 + lane] = acc;
}

// Fused NNConv message + scatter. 64 edges per block, 4 waves split the 64
// output columns (n0 = wave*16). For i in 0..63: P_i = H[64,128] @ We2_i^T
// via mfma_f32_16x16x32_bf16 (A frags cached in regs across the whole i-loop,
// B straight from L2-resident We2bf), then macc += s_i[e] * P_i (fp32 fold).
__global__ __launch_bounds__(256) void msg_fused(const int* __restrict__ ei,
    const float* __restrict__ state, const unsigned short* __restrict__ hidden,
    const unsigned short* __restrict__ We2bf, const float* __restrict__ u,
    float* __restrict__ agg, int E) {
  __shared__ __align__(16) unsigned short Hs[64 * 136];  // [e][l], +8 pad vs bank stride
  __shared__ __align__(16) float St[64 * 64];            // [i][e] transposed s gather
  __shared__ int srcs[64], dsts[64];
  int tid = threadIdx.x;
  int e0 = blockIdx.x * 64;
  if (tid < 64) {
    int e = e0 + tid;
    srcs[tid] = (e < E) ? ei[e] : -1;
    dsts[tid] = (e < E) ? ei[E + e] : -1;
  }
  __syncthreads();
  {
    int er = tid >> 2, part = tid & 3;  // 4 threads/row, 32 shorts each
    int ge = e0 + er;
    const unsigned short* hp = hidden + (size_t)ge * 128 + part * 32;
    #pragma unroll
    for (int j = 0; j < 4; ++j) {
      uint4 v = make_uint4(0u, 0u, 0u, 0u);
      if (ge < E) v = *(const uint4*)(hp + j * 8);
      *(uint4*)&Hs[er * 136 + part * 32 + j * 8] = v;
    }
    int sn = srcs[er];
    int i0 = part * 16;
    #pragma unroll
    for (int j = 0; j < 4; ++j) {
      float4 v = make_float4(0.f, 0.f, 0.f, 0.f);
      if (sn >= 0) v = *(const float4*)(state + (size_t)sn * 64 + i0 + j * 4);
      St[(i0 + j * 4 + 0) * 64 + er] = v.x;
      St[(i0 + j * 4 + 1) * 64 + er] = v.y;
      St[(i0 + j * 4 + 2) * 64 + er] = v.z;
      St[(i0 + j * 4 + 3) * 64 + er] = v.w;
    }
  }
  __syncthreads();
  int lane = tid & 63, wave = tid >> 6;
  int n0 = wave * 16;               // this wave's 16 output columns
  int quad = lane >> 4, col = lane & 15;
  // A fragments: a[mt][kk] = H[mt*16+col][kk*32 + quad*8 + j], j=0..7
  short8 a[4][4];
  #pragma unroll
  for (int mt = 0; mt < 4; ++mt)
    #pragma unroll
    for (int kk = 0; kk < 4; ++kk)
      a[mt][kk] = *(const short8*)&Hs[(mt * 16 + col) * 136 + kk * 32 + quad * 8];
  f32x4 macc[4];
  #pragma unroll
  for (int mt = 0; mt < 4; ++mt) macc[mt] = (f32x4){0.f, 0.f, 0.f, 0.f};

  for (int i = 0; i < 64; ++i) {
    // B frags: b[kk][j] = We2[(i*64 + n0+col)][kk*32 + quad*8 + j]
    const unsigned short* brow = We2bf + ((size_t)i * 64 + n0 + col) * 128 + quad * 8;
    short8 b0v = *(const short8*)(brow + 0);
    short8 b1v = *(const short8*)(brow + 32);
    short8 b2v = *(const short8*)(brow + 64);
    short8 b3v = *(const short8*)(brow + 96);
    #pragma unroll
    for (int mt = 0; mt < 4; ++mt) {
      f32x4 p = (f32x4){0.f, 0.f, 0.f, 0.f};
      p = __builtin_amdgcn_mfma_f32_16x16x32_bf16(a[mt][0], b0v, p, 0, 0, 0);
      p = __builtin_amdgcn_mfma_f32_16x16x32_bf16(a[mt][1], b1v, p, 0, 0, 0);
      p = __builtin_amdgcn_mfma_f32_16x16x32_bf16(a[mt][2], b2v, p, 0, 0, 0);
      p = __builtin_amdgcn_mfma_f32_16x16x32_bf16(a[mt][3], b3v, p, 0, 0, 0);
      f32x4 sv = *(const f32x4*)&St[i * 64 + mt * 16 + quad * 4];  // s[edge rows, i]
      macc[mt] += sv * p;
    }
  }
  // scatter: lane value (mt, r) -> edge mt*16+quad*4+r, column n0+col
  #pragma unroll
  for (int mt = 0; mt < 4; ++mt) {
    #pragma unroll
    for (int r = 0; r < 4; ++r) {
      int el = mt * 16 + quad * 4 + r;
      int d = dsts[el];
      if (d >= 0) {
        float val = macc[mt][r] + u[(size_t)srcs[el] * 64 + n0 + col];
        atomicAdd(&agg[(size_t)d * 64 + n0 + col], val);
      }
    }
  }
}

// m = relu(agg/deg + h@Wroot^T + bconv); h = GRUCell(m, h). One wave per node.
__global__ __launch_bounds__(256) void gru_kernel(const float* __restrict__ agg,
    const float* __restrict__ deg, float* __restrict__ state,
    const float* __restrict__ Wroot, const float* __restrict__ bconv,
    const float* __restrict__ W_ih, const float* __restrict__ W_hh,
    const float* __restrict__ b_ih, const float* __restrict__ b_hh, int N) {
  int lane = threadIdx.x & 63;
  int n = blockIdx.x * 4 + (threadIdx.x >> 6);
  if (n >= N) return;
  float h = state[(size_t)n * 64 + lane];
  float dv = fmaxf(deg[n], 1.0f);
  float am = agg[(size_t)n * 64 + lane] / dv;
  float accm = bconv[lane];
  const float* wr = Wroot + (size_t)lane * 64;
  for (int i = 0; i < 64; ++i) accm += __shfl(h, i) * wr[i];
  float m = fmaxf(am + accm, 0.0f);
  float gir = b_ih[lane], giz = b_ih[64 + lane], gin = b_ih[128 + lane];
  float ghr = b_hh[lane], ghz = b_hh[64 + lane], ghn = b_hh[128 + lane];
  const float* wi0 = W_ih + (size_t)lane * 64;
  const float* wi1 = W_ih + (size_t)(64 + lane) * 64;
  const float* wi2 = W_ih + (size_t)(128 + lane) * 64;
  const float* wh0 = W_hh + (size_t)lane * 64;
  const float* wh1 = W_hh + (size_t)(64 + lane) * 64;
  const float* wh2 = W_hh + (size_t)(128 + lane) * 64;
  for (int i = 0; i < 64; ++i) {
    float mi = __shfl(m, i);
    float hi = __shfl(h, i);
    gir += mi * wi0[i]; giz += mi * wi1[i]; gin += mi * wi2[i];
    ghr += hi * wh0[i]; ghz += hi * wh1[i]; ghn += hi * wh2[i];
  }
  float rg = 1.0f / (1.0f + expf(-(gir + ghr)));
  float zg = 1.0f / (1.0f + expf(-(giz + ghz)));
  float ng = tanhf(gin + rg * ghn);
  state[(size_t)n * 64 + lane] = (1.0f - zg) * ng + zg * h;
}

// out = relu(cat(h, graph_attr[batch]) @ W1^T + b1) @ W2^T + b2. One wave per node.
__global__ __launch_bounds__(256) void final_kernel(const float* __restrict__ state,
    const int* __restrict__ batch, const float* __restrict__ gattr,
    const float* __restrict__ W1, const float* __restrict__ b1,
    const float* __restrict__ W2, const float* __restrict__ b2,
    float* __restrict__ out, int N) {
  int lane = threadIdx.x & 63;
  int n = blockIdx.x * 4 + (threadIdx.x >> 6);
  if (n >= N) return;
  float s = state[(size_t)n * 64 + lane];
  int b = batch[n];
  float acc = b1[lane];
  const float* w = W1 + (size_t)lane * 72;
  for (int i = 0; i < 64; ++i) acc += __shfl(s, i) * w[i];
  const float* gar = gattr + (size_t)b * GDIM;
  #pragma unroll
  for (int j = 0; j < GDIM; ++j) acc += gar[j] * w[64 + j];
  float hid = fmaxf(acc, 0.0f);
  float v = hid * W2[lane];
  #pragma unroll
  for (int off = 32; off > 0; off >>= 1) v += __shfl_xor(v, off);
  if (lane == 0) out[n] = v + b2[0];
}

extern "C" void kernel_launch(void* const* d_in, const int* in_sizes, int n_in,
                              void* d_out, int out_size, void* d_ws, size_t ws_size,
                              hipStream_t stream) {
  const float* x     = (const float*)d_in[0];
  const int*   ei    = (const int*)d_in[1];
  const float* ea    = (const float*)d_in[2];
  const int*   batch = (const int*)d_in[3];
  const float* ga    = (const float*)d_in[4];
  const float* W0    = (const float*)d_in[5];
  const float* b0    = (const float*)d_in[6];
  const float* We1   = (const float*)d_in[7];
  const float* be1   = (const float*)d_in[8];
  const float* We2   = (const float*)d_in[9];
  const float* be2   = (const float*)d_in[10];
  const float* Wroot = (const float*)d_in[11];
  const float* bconv = (const float*)d_in[12];
  const float* W_ih  = (const float*)d_in[13];
  const float* W_hh  = (const float*)d_in[14];
  const float* b_ih  = (const float*)d_in[15];
  const float* b_hh  = (const float*)d_in[16];
  const float* W1    = (const float*)d_in[17];
  const float* b1    = (const float*)d_in[18];
  const float* W2    = (const float*)d_in[19];
  const float* b2    = (const float*)d_in[20];
  int N = in_sizes[0] / FIN;
  int E = in_sizes[1] / 2;
  float* out = (float*)d_out;

  // workspace layout (~21.5 MB total for N=10000, E=50000)
  char* p = (char*)d_ws;
  float* state = (float*)p; p += (size_t)N * 64 * 4;
  float* agg   = (float*)p; p += (size_t)N * 64 * 4;
  float* u     = (float*)p; p += (size_t)N * 64 * 4;
  float* deg   = (float*)p; p += ((size_t)N * 4 + 255) & ~(size_t)255;
  unsigned short* hidden = (unsigned short*)p; p += (size_t)E * 128 * 2;
  unsigned short* We2bf  = (unsigned short*)p; p += (size_t)4096 * 128 * 2;

  int nwBlocks = (N + 3) / 4;
  int msgBlocks = (E + 63) / 64;

  zero_f32<<<(N + 255) / 256, 256, 0, stream>>>(deg, N);
  deg_kernel<<<(E + 255) / 256, 256, 0, stream>>>(ei + E, deg, E);
  lin0_kernel<<<(N * 64 + 255) / 256, 256, 0, stream>>>(x, W0, b0, state, N);
  edge_mlp1<<<(E * 128 + 255) / 256, 256, 0, stream>>>(ea, We1, be1, hidden, E);
  conv_we2<<<(4096 * 128 + 255) / 256, 256, 0, stream>>>(We2, We2bf, 4096 * 128);
  for (int t = 0; t < 3; ++t) {
    zero_f32<<<(N * 64 + 255) / 256, 256, 0, stream>>>(agg, N * 64);
    u_kernel<<<nwBlocks, 256, 0, stream>>>(state, be2, u, N);
    msg_fused<<<msgBlocks, 256, 0, stream>>>(ei, state, hidden, We2bf, u, agg, E);
    gru_kernel<<<nwBlocks, 256, 0, stream>>>(agg, deg, state, Wroot, bconv,
                                             W_ih, W_hh, b_ih, b_hh, N);
  }
  final_kernel<<<nwBlocks, 256, 0, stream>>>(state, batch, ga, W1, b1, W2, b2, out, N);
}

// Round 3
// 633.515 us; speedup vs baseline: 1.8997x; 1.8997x over previous
//
#include <hip/hip_runtime.h>
#include <hip/hip_bf16.h>
#include <math.h>

#define FIN 32
#define EFD 16
#define GDIM 8
// D = 64, DL = 128 hard-coded throughout

typedef __attribute__((ext_vector_type(8))) short short8;   // 8 bf16 = 4 VGPRs (MFMA A/B frag)
typedef __attribute__((ext_vector_type(4))) float f32x4;    // MFMA C/D frag

static __device__ __forceinline__ float bf2f(unsigned short u) {
  return __uint_as_float(((unsigned)u) << 16);
}
static __device__ __forceinline__ unsigned short f2bf(float f) {
  unsigned u = __float_as_uint(f);
  unsigned r = (u + 0x7FFFu + ((u >> 16) & 1u)) >> 16;  // RNE
  return (unsigned short)r;
}

__global__ void zero_f32(float* __restrict__ p, int n) {
  int i = blockIdx.x * blockDim.x + threadIdx.x;
  if (i < n) p[i] = 0.0f;
}

__global__ void deg_kernel(const int* __restrict__ dst, float* __restrict__ deg, int E) {
  int e = blockIdx.x * blockDim.x + threadIdx.x;
  if (e < E) atomicAdd(&deg[dst[e]], 1.0f);
}

// state = relu(x @ W0^T + b0)   [N,64]; lane = output feature
__global__ void lin0_kernel(const float* __restrict__ x, const float* __restrict__ W0,
                            const float* __restrict__ b0, float* __restrict__ state, int N) {
  int idx = blockIdx.x * blockDim.x + threadIdx.x;
  int n = idx >> 6, d = idx & 63;
  if (n >= N) return;
  float acc = b0[d];
  const float* xr = x + (size_t)n * FIN;
  const float* wr = W0 + (size_t)d * FIN;
  #pragma unroll
  for (int f = 0; f < FIN; ++f) acc += xr[f] * wr[f];
  state[idx] = fmaxf(acc, 0.0f);
}

// hidden(bf16) = relu(edge_attr @ We1^T + be1)   [E,128]
__global__ void edge_mlp1(const float* __restrict__ ea, const float* __restrict__ We1,
                          const float* __restrict__ be1, unsigned short* __restrict__ hidden, int E) {
  int idx = blockIdx.x * blockDim.x + threadIdx.x;
  int e = idx >> 7, l = idx & 127;
  if (e >= E) return;
  float acc = be1[l];
  const float* er = ea + (size_t)e * EFD;
  const float* wr = We1 + (size_t)l * EFD;
  #pragma unroll
  for (int j = 0; j < EFD; ++j) acc += er[j] * wr[j];
  hidden[idx] = f2bf(fmaxf(acc, 0.0f));
}

// We2 fp32 [4096,128] -> bf16 copy
__global__ void conv_we2(const float* __restrict__ We2, unsigned short* __restrict__ We2bf, int n) {
  int i = blockIdx.x * blockDim.x + threadIdx.x;
  if (i < n) We2bf[i] = f2bf(We2[i]);
}

// Build hi/lo bf16 weights:
//  Wc [320][64]: rows 0..63 = Wroot, 64..255 = W_hh, 256..319 = Be2^T (be2[i*64+o])
//  Wih [192][64]: W_ih
__global__ void prep_weights(const float* __restrict__ Wroot, const float* __restrict__ W_hh,
                             const float* __restrict__ be2, const float* __restrict__ W_ih,
                             unsigned short* __restrict__ Wc_hi, unsigned short* __restrict__ Wc_lo,
                             unsigned short* __restrict__ Wih_hi, unsigned short* __restrict__ Wih_lo) {
  int idx = blockIdx.x * blockDim.x + threadIdx.x;
  if (idx >= 512 * 64) return;
  int o = idx >> 6, i = idx & 63;
  if (o < 320) {
    float w;
    if (o < 64)       w = Wroot[o * 64 + i];
    else if (o < 256) w = W_hh[(o - 64) * 64 + i];
    else              w = be2[i * 64 + (o - 256)];
    unsigned short h = f2bf(w);
    Wc_hi[idx] = h;
    Wc_lo[idx] = f2bf(w - bf2f(h));
  } else {
    int oo = o - 320;  // 0..191
    float w = W_ih[oo * 64 + i];
    unsigned short h = f2bf(w);
    Wih_hi[oo * 64 + i] = h;
    Wih_lo[oo * 64 + i] = f2bf(w - bf2f(h));
  }
}

#define MFMA(A, B, C) __builtin_amdgcn_mfma_f32_16x16x32_bf16((A), (B), (C), 0, 0, 0)

// R[N,320] = state @ Wc^T  (fp32-accurate via hi/lo bf16 split, 3 MFMAs per product)
// 64 nodes per block; wave w covers output cols [80w, 80w+80).
__global__ __launch_bounds__(256) void pre_kernel(const float* __restrict__ state,
    const unsigned short* __restrict__ Wc_hi, const unsigned short* __restrict__ Wc_lo,
    float* __restrict__ R, int N) {
  __shared__ __align__(16) unsigned short Sh[64 * 72], Sl[64 * 72];
  int tid = threadIdx.x;
  int n0 = blockIdx.x * 64;
  {
    int nl = tid >> 2, part = tid & 3;
    int gn = n0 + nl;
    const float* sp = state + (size_t)gn * 64 + part * 16;
    #pragma unroll
    for (int j = 0; j < 4; ++j) {
      float4 v = make_float4(0.f, 0.f, 0.f, 0.f);
      if (gn < N) v = *(const float4*)(sp + j * 4);
      int base = nl * 72 + part * 16 + j * 4;
      unsigned short h;
      h = f2bf(v.x); Sh[base + 0] = h; Sl[base + 0] = f2bf(v.x - bf2f(h));
      h = f2bf(v.y); Sh[base + 1] = h; Sl[base + 1] = f2bf(v.y - bf2f(h));
      h = f2bf(v.z); Sh[base + 2] = h; Sl[base + 2] = f2bf(v.z - bf2f(h));
      h = f2bf(v.w); Sh[base + 3] = h; Sl[base + 3] = f2bf(v.w - bf2f(h));
    }
  }
  __syncthreads();
  int lane = tid & 63, wave = tid >> 6;
  int quad = lane >> 4, mcol = lane & 15;
  short8 ah[4][2], al[4][2];
  #pragma unroll
  for (int mt = 0; mt < 4; ++mt)
    #pragma unroll
    for (int kk = 0; kk < 2; ++kk) {
      ah[mt][kk] = *(const short8*)&Sh[(mt * 16 + mcol) * 72 + kk * 32 + quad * 8];
      al[mt][kk] = *(const short8*)&Sl[(mt * 16 + mcol) * 72 + kk * 32 + quad * 8];
    }
  int c0w = wave * 80;
  for (int cg = 0; cg < 5; ++cg) {
    int c = c0w + cg * 16 + mcol;
    const unsigned short* bhp = Wc_hi + (size_t)c * 64 + quad * 8;
    const unsigned short* blp = Wc_lo + (size_t)c * 64 + quad * 8;
    short8 bh0 = *(const short8*)bhp, bh1 = *(const short8*)(bhp + 32);
    short8 bl0 = *(const short8*)blp, bl1 = *(const short8*)(blp + 32);
    #pragma unroll
    for (int mt = 0; mt < 4; ++mt) {
      f32x4 p = (f32x4){0.f, 0.f, 0.f, 0.f};
      p = MFMA(al[mt][0], bh0, p);
      p = MFMA(ah[mt][0], bl0, p);
      p = MFMA(ah[mt][0], bh0, p);
      p = MFMA(al[mt][1], bh1, p);
      p = MFMA(ah[mt][1], bl1, p);
      p = MFMA(ah[mt][1], bh1, p);
      #pragma unroll
      for (int r = 0; r < 4; ++r) {
        int row = n0 + mt * 16 + quad * 4 + r;
        if (row < N) R[(size_t)row * 320 + c] = p[r];
      }
    }
  }
}

// Fused NNConv message + scatter. 64 edges per block, 4 waves split the 64
// output columns. u (bias term) read from R[:,256:320].
__global__ __launch_bounds__(256) void msg_fused(const int* __restrict__ ei,
    const float* __restrict__ state, const unsigned short* __restrict__ hidden,
    const unsigned short* __restrict__ We2bf, const float* __restrict__ R,
    float* __restrict__ agg, int E) {
  __shared__ __align__(16) unsigned short Hs[64 * 136];
  __shared__ __align__(16) float St[64 * 64];
  __shared__ int srcs[64], dsts[64];
  int tid = threadIdx.x;
  int e0 = blockIdx.x * 64;
  if (tid < 64) {
    int e = e0 + tid;
    srcs[tid] = (e < E) ? ei[e] : -1;
    dsts[tid] = (e < E) ? ei[E + e] : -1;
  }
  __syncthreads();
  {
    int er = tid >> 2, part = tid & 3;
    int ge = e0 + er;
    const unsigned short* hp = hidden + (size_t)ge * 128 + part * 32;
    #pragma unroll
    for (int j = 0; j < 4; ++j) {
      uint4 v = make_uint4(0u, 0u, 0u, 0u);
      if (ge < E) v = *(const uint4*)(hp + j * 8);
      *(uint4*)&Hs[er * 136 + part * 32 + j * 8] = v;
    }
    int sn = srcs[er];
    int i0 = part * 16;
    #pragma unroll
    for (int j = 0; j < 4; ++j) {
      float4 v = make_float4(0.f, 0.f, 0.f, 0.f);
      if (sn >= 0) v = *(const float4*)(state + (size_t)sn * 64 + i0 + j * 4);
      St[(i0 + j * 4 + 0) * 64 + er] = v.x;
      St[(i0 + j * 4 + 1) * 64 + er] = v.y;
      St[(i0 + j * 4 + 2) * 64 + er] = v.z;
      St[(i0 + j * 4 + 3) * 64 + er] = v.w;
    }
  }
  __syncthreads();
  int lane = tid & 63, wave = tid >> 6;
  int n0 = wave * 16;
  int quad = lane >> 4, col = lane & 15;
  short8 a[4][4];
  #pragma unroll
  for (int mt = 0; mt < 4; ++mt)
    #pragma unroll
    for (int kk = 0; kk < 4; ++kk)
      a[mt][kk] = *(const short8*)&Hs[(mt * 16 + col) * 136 + kk * 32 + quad * 8];
  f32x4 macc[4];
  #pragma unroll
  for (int mt = 0; mt < 4; ++mt) macc[mt] = (f32x4){0.f, 0.f, 0.f, 0.f};

  for (int i = 0; i < 64; ++i) {
    const unsigned short* brow = We2bf + ((size_t)i * 64 + n0 + col) * 128 + quad * 8;
    short8 b0v = *(const short8*)(brow + 0);
    short8 b1v = *(const short8*)(brow + 32);
    short8 b2v = *(const short8*)(brow + 64);
    short8 b3v = *(const short8*)(brow + 96);
    #pragma unroll
    for (int mt = 0; mt < 4; ++mt) {
      f32x4 p = (f32x4){0.f, 0.f, 0.f, 0.f};
      p = MFMA(a[mt][0], b0v, p);
      p = MFMA(a[mt][1], b1v, p);
      p = MFMA(a[mt][2], b2v, p);
      p = MFMA(a[mt][3], b3v, p);
      f32x4 sv = *(const f32x4*)&St[i * 64 + mt * 16 + quad * 4];
      macc[mt] += sv * p;
    }
  }
  #pragma unroll
  for (int mt = 0; mt < 4; ++mt) {
    #pragma unroll
    for (int r = 0; r < 4; ++r) {
      int el = mt * 16 + quad * 4 + r;
      int d = dsts[el];
      if (d >= 0) {
        float val = macc[mt][r] + R[(size_t)srcs[el] * 320 + 256 + n0 + col];
        atomicAdd(&agg[(size_t)d * 64 + n0 + col], val);
      }
    }
  }
}

// Fused: m = relu(agg/deg + R.root + bconv); gi = m@W_ih^T (hi/lo MFMA);
// gates + state update; re-zeros agg for the next iteration.
// 64 nodes per block; wave w covers gate cols [16w, 16w+16).
__global__ __launch_bounds__(256) void gate_fused(float* __restrict__ agg,
    const float* __restrict__ deg, float* __restrict__ state,
    const float* __restrict__ R, const float* __restrict__ bconv,
    const unsigned short* __restrict__ Wih_hi, const unsigned short* __restrict__ Wih_lo,
    const float* __restrict__ b_ih, const float* __restrict__ b_hh, int N) {
  __shared__ __align__(16) unsigned short Mh[64 * 72], Ml[64 * 72];
  int tid = threadIdx.x;
  int n0 = blockIdx.x * 64;
  {
    int nl = tid >> 2, part = tid & 3;
    int gn = n0 + nl;
    float inv = 1.0f;
    if (gn < N) inv = 1.0f / fmaxf(deg[gn], 1.0f);
    #pragma unroll
    for (int j = 0; j < 4; ++j) {
      int o = part * 16 + j * 4;
      float4 av = make_float4(0.f, 0.f, 0.f, 0.f);
      float4 rv = make_float4(0.f, 0.f, 0.f, 0.f);
      if (gn < N) {
        av = *(const float4*)(agg + (size_t)gn * 64 + o);
        rv = *(const float4*)(R + (size_t)gn * 320 + o);
      }
      float4 bv = *(const float4*)(bconv + o);
      float m0 = fmaxf(av.x * inv + rv.x + bv.x, 0.0f);
      float m1 = fmaxf(av.y * inv + rv.y + bv.y, 0.0f);
      float m2 = fmaxf(av.z * inv + rv.z + bv.z, 0.0f);
      float m3 = fmaxf(av.w * inv + rv.w + bv.w, 0.0f);
      int base = nl * 72 + o;
      unsigned short h;
      h = f2bf(m0); Mh[base + 0] = h; Ml[base + 0] = f2bf(m0 - bf2f(h));
      h = f2bf(m1); Mh[base + 1] = h; Ml[base + 1] = f2bf(m1 - bf2f(h));
      h = f2bf(m2); Mh[base + 2] = h; Ml[base + 2] = f2bf(m2 - bf2f(h));
      h = f2bf(m3); Mh[base + 3] = h; Ml[base + 3] = f2bf(m3 - bf2f(h));
      if (gn < N)
        *(float4*)(agg + (size_t)gn * 64 + o) = make_float4(0.f, 0.f, 0.f, 0.f);
    }
  }
  __syncthreads();
  int lane = tid & 63, wave = tid >> 6;
  int quad = lane >> 4, mcol = lane & 15;
  short8 ah[4][2], al[4][2];
  #pragma unroll
  for (int mt = 0; mt < 4; ++mt)
    #pragma unroll
    for (int kk = 0; kk < 2; ++kk) {
      ah[mt][kk] = *(const short8*)&Mh[(mt * 16 + mcol) * 72 + kk * 32 + quad * 8];
      al[mt][kk] = *(const short8*)&Ml[(mt * 16 + mcol) * 72 + kk * 32 + quad * 8];
    }
  int c = wave * 16 + mcol;
  f32x4 acc[3];
  #pragma unroll
  for (int g = 0; g < 3; ++g) acc[g] = (f32x4){0.f, 0.f, 0.f, 0.f};
  #pragma unroll
  for (int mt = 0; mt < 4; ++mt) { (void)mt; }  // (acc is per-gate per-mt below)
  f32x4 accg[3][4];
  #pragma unroll
  for (int g = 0; g < 3; ++g) {
    const unsigned short* bhp = Wih_hi + (size_t)(g * 64 + c) * 64 + quad * 8;
    const unsigned short* blp = Wih_lo + (size_t)(g * 64 + c) * 64 + quad * 8;
    short8 bh0 = *(const short8*)bhp, bh1 = *(const short8*)(bhp + 32);
    short8 bl0 = *(const short8*)blp, bl1 = *(const short8*)(blp + 32);
    #pragma unroll
    for (int mt = 0; mt < 4; ++mt) {
      f32x4 p = (f32x4){0.f, 0.f, 0.f, 0.f};
      p = MFMA(al[mt][0], bh0, p);
      p = MFMA(ah[mt][0], bl0, p);
      p = MFMA(ah[mt][0], bh0, p);
      p = MFMA(al[mt][1], bh1, p);
      p = MFMA(ah[mt][1], bl1, p);
      p = MFMA(ah[mt][1], bh1, p);
      accg[g][mt] = p;
    }
  }
  float bir = b_ih[c], biz = b_ih[64 + c], bin = b_ih[128 + c];
  float bhr = b_hh[c], bhz = b_hh[64 + c], bhn = b_hh[128 + c];
  #pragma unroll
  for (int mt = 0; mt < 4; ++mt) {
    #pragma unroll
    for (int r = 0; r < 4; ++r) {
      int node = n0 + mt * 16 + quad * 4 + r;
      if (node >= N) continue;
      const float* Rn = R + (size_t)node * 320;
      float gir = accg[0][mt][r] + bir + Rn[64 + c] + bhr;
      float giz = accg[1][mt][r] + biz + Rn[128 + c] + bhz;
      float ghn = Rn[192 + c] + bhn;
      float rg = 1.0f / (1.0f + expf(-gir));
      float zg = 1.0f / (1.0f + expf(-giz));
      float ng = tanhf(accg[2][mt][r] + bin + rg * ghn);
      size_t si = (size_t)node * 64 + c;
      float h = state[si];
      state[si] = (1.0f - zg) * ng + zg * h;
    }
  }
}

// out = relu(cat(h, graph_attr[batch]) @ W1^T + b1) @ W2^T + b2. One wave per node.
__global__ __launch_bounds__(256) void final_kernel(const float* __restrict__ state,
    const int* __restrict__ batch, const float* __restrict__ gattr,
    const float* __restrict__ W1, const float* __restrict__ b1,
    const float* __restrict__ W2, const float* __restrict__ b2,
    float* __restrict__ out, int N) {
  int lane = threadIdx.x & 63;
  int n = blockIdx.x * 4 + (threadIdx.x >> 6);
  if (n >= N) return;
  float s = state[(size_t)n * 64 + lane];
  int b = batch[n];
  float acc = b1[lane];
  const float* w = W1 + (size_t)lane * 72;
  for (int i = 0; i < 64; ++i) acc += __shfl(s, i) * w[i];
  const float* gar = gattr + (size_t)b * GDIM;
  #pragma unroll
  for (int j = 0; j < GDIM; ++j) acc += gar[j] * w[64 + j];
  float hid = fmaxf(acc, 0.0f);
  float v = hid * W2[lane];
  #pragma unroll
  for (int off = 32; off > 0; off >>= 1) v += __shfl_xor(v, off);
  if (lane == 0) out[n] = v + b2[0];
}

extern "C" void kernel_launch(void* const* d_in, const int* in_sizes, int n_in,
                              void* d_out, int out_size, void* d_ws, size_t ws_size,
                              hipStream_t stream) {
  const float* x     = (const float*)d_in[0];
  const int*   ei    = (const int*)d_in[1];
  const float* ea    = (const float*)d_in[2];
  const int*   batch = (const int*)d_in[3];
  const float* ga    = (const float*)d_in[4];
  const float* W0    = (const float*)d_in[5];
  const float* b0    = (const float*)d_in[6];
  const float* We1   = (const float*)d_in[7];
  const float* be1   = (const float*)d_in[8];
  const float* We2   = (const float*)d_in[9];
  const float* be2   = (const float*)d_in[10];
  const float* Wroot = (const float*)d_in[11];
  const float* bconv = (const float*)d_in[12];
  const float* W_ih  = (const float*)d_in[13];
  const float* W_hh  = (const float*)d_in[14];
  const float* b_ih  = (const float*)d_in[15];
  const float* b_hh  = (const float*)d_in[16];
  const float* W1    = (const float*)d_in[17];
  const float* b1    = (const float*)d_in[18];
  const float* W2    = (const float*)d_in[19];
  const float* b2    = (const float*)d_in[20];
  int N = in_sizes[0] / FIN;
  int E = in_sizes[1] / 2;
  float* out = (float*)d_out;

  // workspace (~32 MB for N=10000, E=50000)
  char* p = (char*)d_ws;
  float* state = (float*)p; p += (size_t)N * 64 * 4;
  float* agg   = (float*)p; p += (size_t)N * 64 * 4;
  float* deg   = (float*)p; p += ((size_t)N * 4 + 15) & ~(size_t)15;  // contiguous after agg
  float* R     = (float*)p; p += (size_t)N * 320 * 4;
  unsigned short* hidden = (unsigned short*)p; p += (size_t)E * 128 * 2;
  unsigned short* We2bf  = (unsigned short*)p; p += (size_t)4096 * 128 * 2;
  unsigned short* Wc_hi  = (unsigned short*)p; p += 320 * 64 * 2;
  unsigned short* Wc_lo  = (unsigned short*)p; p += 320 * 64 * 2;
  unsigned short* Wih_hi = (unsigned short*)p; p += 192 * 64 * 2;
  unsigned short* Wih_lo = (unsigned short*)p; p += 192 * 64 * 2;
  if ((size_t)(p - (char*)d_ws) > ws_size) return;  // visible failure if ws too small

  int tileBlocks = (N + 63) / 64;
  int msgBlocks  = (E + 63) / 64;

  zero_f32<<<(N * 65 + 255) / 256, 256, 0, stream>>>(agg, N * 65);  // agg + deg contiguous
  deg_kernel<<<(E + 255) / 256, 256, 0, stream>>>(ei + E, deg, E);
  lin0_kernel<<<(N * 64 + 255) / 256, 256, 0, stream>>>(x, W0, b0, state, N);
  edge_mlp1<<<(E * 128 + 255) / 256, 256, 0, stream>>>(ea, We1, be1, hidden, E);
  conv_we2<<<(4096 * 128 + 255) / 256, 256, 0, stream>>>(We2, We2bf, 4096 * 128);
  prep_weights<<<(512 * 64 + 255) / 256, 256, 0, stream>>>(Wroot, W_hh, be2, W_ih,
                                                           Wc_hi, Wc_lo, Wih_hi, Wih_lo);
  for (int t = 0; t < 3; ++t) {
    pre_kernel<<<tileBlocks, 256, 0, stream>>>(state, Wc_hi, Wc_lo, R, N);
    msg_fused<<<msgBlocks, 256, 0, stream>>>(ei, state, hidden, We2bf, R, agg, E);
    gate_fused<<<tileBlocks, 256, 0, stream>>>(agg, deg, state, R, bconv,
                                               Wih_hi, Wih_lo, b_ih, b_hh, N);
  }
  final_kernel<<<(N + 3) / 4, 256, 0, stream>>>(state, batch, ga, W1, b1, W2, b2, out, N);
}